// Round 10
// baseline (165.372 us; speedup 1.0000x reference)
//
#include <hip/hip_runtime.h>
#include <hip/hip_bf16.h>
#include <math.h>

// Problem constants (B, Cin, Cmid, H, W) = (2, 256, 128, 112, 112), R=3
constexpr int B    = 2;
constexpr int CIN  = 256;
constexpr int CMID = 128;
constexpr int H    = 112;
constexpr int W    = 112;
constexpr int HW   = H * W;        // 12544
constexpr int NPIX = B * HW;       // 25088
constexpr int RAD  = 3;
constexpr int KS   = 7;
constexpr int DD   = 49;

typedef __attribute__((ext_vector_type(8))) short  short8;   // 8 bf16 (4 VGPR)
typedef __attribute__((ext_vector_type(4))) float  float4v;  // MFMA C/D

// hardware v_cvt_pk_bf16_f32 (RNE) via HIP intrinsic
__device__ __forceinline__ unsigned pkbf(float a, float b) {
    union { __hip_bfloat162 h; unsigned u; } c;
    c.h = __float22bfloat162_rn(make_float2(a, b));
    return c.u;
}

// ---------------------------------------------------------------------------
// Kernel 1: q = l2norm(Wq @ phi_cur), k = l2norm(Wk @ phi_rnd)  via bf16 MFMA.
// (unchanged from round 9 — isolating the corr phase-C transpose)
// ---------------------------------------------------------------------------
constexpr int PSTR = 264;           // shorts per pixel row in pt

__global__ __launch_bounds__(256) void proj_mfma(
    const float* __restrict__ phi_cur, const float* __restrict__ phi_rnd,
    const float* __restrict__ Wq, const float* __restrict__ Wk,
    unsigned short* __restrict__ q_ws, unsigned short* __restrict__ k_ws)
{
    __shared__ unsigned short pt[64 * PSTR];  // 33,792 B  pixel-major bf16
    __shared__ float red[4][64];

    const int tid  = threadIdx.x;
    const int lane = tid & 63;
    const int wv   = __builtin_amdgcn_readfirstlane(tid >> 6);
    const int t    = blockIdx.y;                    // 0 -> q, 1 -> k

    const float* __restrict__ phi = t ? phi_rnd : phi_cur;
    const float* __restrict__ Wm  = t ? Wk : Wq;
    unsigned short* __restrict__ outp = t ? k_ws : q_ws;

    const int pgb = blockIdx.x * 64;                // 64-aligned, no b crossing
    const int b   = pgb / HW;
    const int pim = pgb % HW;
    const float* pbase = phi + (size_t)b * CIN * HW + pim;

    // ---- stage phi tile: 8 passes; thread -> (channel-pair, pixel-quad) ----
#pragma unroll
    for (int pass = 0; pass < 8; ++pass) {
        const int idx = pass * 256 + tid;
        const int cp  = idx >> 4;          // channel pair 0..127
        const int pq  = idx & 15;          // pixel quad  0..15
        const int c0  = cp * 2;
        const float4 va = *(const float4*)(pbase + (size_t)c0 * HW + pq * 4);
        const float4 vb = *(const float4*)(pbase + (size_t)(c0 + 1) * HW + pq * 4);
        *(unsigned*)(pt + (pq * 4 + 0) * PSTR + c0) = pkbf(va.x, vb.x);
        *(unsigned*)(pt + (pq * 4 + 1) * PSTR + c0) = pkbf(va.y, vb.y);
        *(unsigned*)(pt + (pq * 4 + 2) * PSTR + c0) = pkbf(va.z, vb.z);
        *(unsigned*)(pt + (pq * 4 + 3) * PSTR + c0) = pkbf(va.w, vb.w);
    }

    // ---- A-frags: this wave's 32 W rows, fp32 loads + in-reg bf16 pack ----
    const int m = lane & 15, quad = lane >> 4;
    short8 af[2][8];
#pragma unroll
    for (int ot = 0; ot < 2; ++ot)
#pragma unroll
        for (int kc = 0; kc < 8; ++kc) {
            const float* wr = Wm + (size_t)(wv * 32 + ot * 16 + m) * CIN
                                 + kc * 32 + quad * 8;
            const float4 w0 = *(const float4*)(wr);
            const float4 w1 = *(const float4*)(wr + 4);
            union { short8 s; unsigned u[4]; } pk;
            pk.u[0] = pkbf(w0.x, w0.y);
            pk.u[1] = pkbf(w0.z, w0.w);
            pk.u[2] = pkbf(w1.x, w1.y);
            pk.u[3] = pkbf(w1.z, w1.w);
            af[ot][kc] = pk.s;
        }

    __syncthreads();

    // ---- MFMA: 2 out-tiles x 4 pixel-tiles x K=256 ----
    float4v acc[2][4];
#pragma unroll
    for (int ot = 0; ot < 2; ++ot)
#pragma unroll
        for (int nt = 0; nt < 4; ++nt) acc[ot][nt] = (float4v)0.f;

#pragma unroll
    for (int kc = 0; kc < 8; ++kc) {
        short8 bf[4];
#pragma unroll
        for (int nt = 0; nt < 4; ++nt)
            bf[nt] = *(const short8*)(pt + (nt * 16 + m) * PSTR + kc * 32 + quad * 8);
#pragma unroll
        for (int ot = 0; ot < 2; ++ot)
#pragma unroll
            for (int nt = 0; nt < 4; ++nt)
                acc[ot][nt] = __builtin_amdgcn_mfma_f32_16x16x32_bf16(
                    af[ot][kc], bf[nt], acc[ot][nt], 0, 0, 0);
    }

    // ---- per-pixel L2 norm: C layout col=lane&15=pixel, row=quad*4+reg=och
#pragma unroll
    for (int nt = 0; nt < 4; ++nt) {
        float ss = 0.f;
#pragma unroll
        for (int ot = 0; ot < 2; ++ot)
#pragma unroll
            for (int r = 0; r < 4; ++r)
                ss = fmaf(acc[ot][nt][r], acc[ot][nt][r], ss);
        ss += __shfl_xor(ss, 16, 64);
        ss += __shfl_xor(ss, 32, 64);
        if (quad == 0) red[wv][nt * 16 + m] = ss;
    }
    __syncthreads();

    float inv[4];
#pragma unroll
    for (int nt = 0; nt < 4; ++nt) {
        const int px = nt * 16 + m;
        const float tot = red[0][px] + red[1][px] + red[2][px] + red[3][px];
        inv[nt] = 1.f / fmaxf(sqrtf(tot), 1e-12f);
    }

    // ---- store bf16 pixel-major ----
#pragma unroll
    for (int nt = 0; nt < 4; ++nt)
#pragma unroll
        for (int ot = 0; ot < 2; ++ot) {
            uint2 st;
            st.x = pkbf(acc[ot][nt][0] * inv[nt], acc[ot][nt][1] * inv[nt]);
            st.y = pkbf(acc[ot][nt][2] * inv[nt], acc[ot][nt][3] * inv[nt]);
            *(uint2*)(outp + (size_t)(pgb + nt * 16 + m) * CMID
                      + wv * 32 + ot * 16 + quad * 4) = st;
        }
}

// ---------------------------------------------------------------------------
// Kernel 2 (ROUND 10: phase-C TRANSPOSED).  Block = 64 pixels (4 rows x 16
// cols), grid (7, 28, 2).
// Phase B: MFMA band-GEMM with global fragment loads (r9 style): 56 groups
// (4 q-rows x 7 k-rows x 2 n-tiles), band-extract into cs[64][53] (stride 53
// dwords: 53 mod 32 coprime -> phase-C row reads are a bank permutation).
// Phase C: lane = PIXEL.  corr[49] -> VGPRs once; rolled d-loop: 49-FMA
// matvec with Wv rows WAVE-UNIFORM (readfirstlane(d) -> s_load, SMEM pipe),
// geometry from small LDS P_rnd tile, ONLINE softmax (no lmax pre-pass, no
// shuffles, no masked lanes), coalesced stores.
// Rationale: r5-r9 corr stuck at ~40-43 us; invariant was phase C's lane=d
// layout: ~4.8k DS-pipe cyc/block (broadcast reads + 96 swizzles) + per-lane
// Wv gather. This rewrite reduces phase-C DS to ~450 cyc/block and deletes
// all shuffles.
// ---------------------------------------------------------------------------
constexpr int BH   = 4;             // tile rows
constexpr int BW   = 16;            // tile cols
constexpr int PRH  = BH + 6;        // 10 P_rnd tile rows
constexpr int PRW  = BW + 6;        // 22 P_rnd tile cols
constexpr int PRN  = PRH * PRW;     // 220 slots per channel
constexpr int CSTR = 53;            // cs row stride (dwords), coprime with 32

__global__ __launch_bounds__(256, 4) void corr_kernel(
    const unsigned short* __restrict__ q_ws, const unsigned short* __restrict__ k_ws,
    const float* __restrict__ P_cur, const float* __restrict__ P_rnd,
    const float* __restrict__ Wvm, const float* __restrict__ bv,
    const float* __restrict__ gamma_p, float* __restrict__ out)
{
    __shared__ float cs[64 * CSTR];     // 13,568 B corr vectors
    __shared__ float prt[3 * PRN];      //  2,640 B P_rnd tile

    const int tid  = threadIdx.x;
    const int lane = tid & 63;
    const int wv   = __builtin_amdgcn_readfirstlane(tid >> 6);
    const int w0   = blockIdx.x * BW;
    const int h0   = blockIdx.y * BH;
    const int b    = blockIdx.z;

    // ---- stage P_rnd tile (3 ch x 10 x 22; zeros OOB = ref padding) ----
#pragma unroll
    for (int pass = 0; pass < 3; ++pass) {
        const int idx = pass * 256 + tid;
        if (idx < 3 * PRN) {
            const int ch = idx / PRN;
            const int sl = idx % PRN;
            const int rr = sl / PRW;
            const int cc = sl % PRW;
            const int hh = h0 + rr - RAD;
            const int ww = w0 + cc - RAD;
            float v = 0.f;
            if (hh >= 0 && hh < H && ww >= 0 && ww < W)
                v = P_rnd[((size_t)b * 3 + ch) * HW + hh * W + ww];
            prt[idx] = v;
        }
    }

    // ---- phase B: MFMA band-GEMM, fragments direct from global ----
    // groups g = hq*14 + r*2 + nt;  wave handles g = wv, wv+4, ...
    const int m = lane & 15, quad = lane >> 4;
    for (int g = wv; g < 56; g += 4) {
        const int hq = g / 14;
        const int rem = g % 14;
        const int r  = rem >> 1;            // k row 0..6
        const int nt = rem & 1;             // n-tile
        const int hh = h0 + hq + r - RAD;
        const int ww = w0 + nt * 16 + m - RAD;
        const bool inb = (hh >= 0) && (hh < H) && (ww >= 0) && (ww < W);
        const unsigned short* qbase =
            q_ws + (size_t)(b * HW + (h0 + hq) * W + w0 + m) * CMID + quad * 8;
        const unsigned short* kbase =
            k_ws + (size_t)(b * HW + hh * W + ww) * CMID + quad * 8;

        float4v acc = (float4v)0.f;
#pragma unroll
        for (int kc = 0; kc < 4; ++kc) {
            const short8 afrag = *(const short8*)(qbase + kc * 32);
            const short8 bfrag = inb ? *(const short8*)(kbase + kc * 32)
                                     : (short8)0;
            acc = __builtin_amdgcn_mfma_f32_16x16x32_bf16(afrag, bfrag, acc, 0, 0, 0);
        }
        // band extract: D row = q pixel col p = quad*4+reg, col cc = nt*16+m
#pragma unroll
        for (int reg = 0; reg < 4; ++reg) {
            const int p   = quad * 4 + reg;
            const int off = nt * 16 + m - p;     // dx + RAD
            if (off >= 0 && off <= 6)
                cs[(hq * 16 + p) * CSTR + r * 7 + off] = acc[reg];
        }
    }
    __syncthreads();

    // ---- phase C: lane = pixel; online softmax over d ----
    const int hq = lane >> 4;           // tile row 0..3
    const int pq = lane & 15;           // tile col 0..15
    const int h  = h0 + hq;
    const int w  = w0 + pq;
    const int pg = b * HW + h * W + w;

    // this pixel's correlation vector -> VGPRs (bank-permuted, conflict-free)
    float cr[DD];
#pragma unroll
    for (int e = 0; e < DD; ++e) cr[e] = cs[lane * CSTR + e];

    const float* pc = P_cur + (size_t)b * 3 * HW + h * W + w;   // coalesced
    const float cx = pc[0], cy = pc[HW], cz = pc[2 * HW];
    const float gamma = gamma_p[0];

    float m_run = -INFINITY, s0 = 0.f, s1 = 0.f, s2 = 0.f;
    int dyr = 0, dxc = 0;
    for (int d = 0; d < DD; ++d) {
        const int du = __builtin_amdgcn_readfirstlane(d);   // force scalar
        const float* wrow = Wvm + du * DD;                  // -> s_load
        float lg = bv[du];
#pragma unroll
        for (int e = 0; e < DD; ++e)
            lg = fmaf(wrow[e], cr[e], lg);

        const int vi = (hq + dyr) * PRW + pq + dxc;
        const float rx = prt[vi];
        const float ry = prt[PRN + vi];
        const float rz = prt[2 * PRN + vi];
        const float dpx = cx - rx, dpy = cy - ry, dpz = cz - rz;
        const float dist = sqrtf(fmaxf(dpx * dpx + dpy * dpy + dpz * dpz, 1e-12f));
        lg += gamma * (-dist - 0.5f * fabsf(dpz));

        // online softmax update (3 moments)
        const float fdx = (float)(dxc - RAD), fdy = (float)(dyr - RAD);
        const float nm = fmaxf(m_run, lg);
        const float sc = __expf(m_run - nm);    // exp(-INF)=0 on first iter
        const float e1 = __expf(lg - nm);
        s0 = fmaf(s0, sc, e1);
        s1 = fmaf(s1, sc, e1 * fdx);
        s2 = fmaf(s2, sc, e1 * fdy);
        m_run = nm;

        if (++dxc == KS) { dxc = 0; ++dyr; }
    }

    const float rZ = 1.f / s0;
    out[pg]            = s1 * rZ;   // du   (coalesced, all 64 lanes)
    out[NPIX + pg]     = s2 * rZ;   // dv
    out[2 * NPIX + pg] = rZ;        // conf = max w  (e_max = 1)
}

// ---------------------------------------------------------------------------
extern "C" void kernel_launch(void* const* d_in, const int* in_sizes, int n_in,
                              void* d_out, int out_size, void* d_ws, size_t ws_size,
                              hipStream_t stream)
{
    const float* phi_cur = (const float*)d_in[0];
    const float* phi_rnd = (const float*)d_in[1];
    const float* P_cur   = (const float*)d_in[2];
    const float* P_rnd   = (const float*)d_in[3];
    const float* Wq      = (const float*)d_in[4];
    const float* Wk      = (const float*)d_in[5];
    const float* Wv      = (const float*)d_in[6];
    const float* bv      = (const float*)d_in[7];
    const float* gm      = (const float*)d_in[8];
    float* out = (float*)d_out;

    unsigned short* ws   = (unsigned short*)d_ws;
    unsigned short* q_ws = ws;                                  // NPIX*CMID bf16
    unsigned short* k_ws = q_ws + (size_t)NPIX * CMID;          // NPIX*CMID bf16

    proj_mfma<<<dim3(NPIX / 64, 2), 256, 0, stream>>>(
        phi_cur, phi_rnd, Wq, Wk, q_ws, k_ws);

    corr_kernel<<<dim3(W / BW, H / BH, B), 256, 0, stream>>>(
        q_ws, k_ws, P_cur, P_rnd, Wv, bv, gm, out);
}